// Round 8
// baseline (253.784 us; speedup 1.0000x reference)
//
#include <hip/hip_runtime.h>
#include <hip/hip_bf16.h>

// MultiHeadAttention: B=4, N=2048, D=1024, H=16, HD=64, causal.
// Contract: f32 inputs AND f32 output; bf16 internal compute.
// R17 = R16 +
//  - gemm: BK 32->64 as TWO [128][32] K-panels (staging stays linear for
//    global_load_lds; fragment reads keep the 64B-stride pattern -> no new
//    bank conflicts). 16 K-iters (was 32): half the barrier/drain count.
//    Operands loaded per-ks so VGPR stays ~80-90.
//  - gemm MODE0 epilogue in two 64-row passes: Cs 17408 -> 8704 elems; LDS
//    = As+Bs = 32768 B -> 5 blocks/CU (was 4).
//  - flash: s_setprio(1) around QK and PV MFMA clusters (T5).
//  - convert_x: one bf16x8 (16B) store per thread (was 4x scalar 2B).

#define BB 4
#define NN 2048
#define DD 1024
#define HH 16
#define HD 64
#define MM (BB * NN) // 8192

typedef __bf16 bf16;
typedef __bf16 bf16x4 __attribute__((ext_vector_type(4)));
typedef __bf16 bf16x8 __attribute__((ext_vector_type(8)));
typedef float f32x4 __attribute__((ext_vector_type(4)));

// Async 16B global->LDS copy. LDS dest must follow wave-uniform base + lane*16.
__device__ __forceinline__ void async_copy16(bf16* lds, const bf16* g) {
    __builtin_amdgcn_global_load_lds(
        (const __attribute__((address_space(1))) void*)g,
        (__attribute__((address_space(3))) void*)lds, 16, 0, 0);
}

// ---------------------------------------------------------------------------
// x: f32 [B*N*D] -> bf16 (8 elems/thread, one 16B store)
// ---------------------------------------------------------------------------
__global__ void convert_x(const float* __restrict__ x, bf16* __restrict__ xb) {
    int i = (blockIdx.x * 256 + threadIdx.x) * 8;
    float4 a = *(const float4*)&x[i];
    float4 b = *(const float4*)&x[i + 4];
    bf16x8 o;
    o[0] = (bf16)a.x; o[1] = (bf16)a.y; o[2] = (bf16)a.z; o[3] = (bf16)a.w;
    o[4] = (bf16)b.x; o[5] = (bf16)b.y; o[6] = (bf16)b.z; o[7] = (bf16)b.w;
    *(bf16x8*)&xb[i] = o;
}

// ---------------------------------------------------------------------------
// Weight transpose + convert (all 4 weights in one launch, z selects):
// Wt[z][n][k] = (bf16)W_z[k][n]  (D x D)
// ---------------------------------------------------------------------------
__global__ void transpose_w4(const float* __restrict__ W0, const float* __restrict__ W1,
                             const float* __restrict__ W2, const float* __restrict__ W3,
                             bf16* __restrict__ Wt) {
    __shared__ float tile[32][33];
    const float* W = (blockIdx.z == 0) ? W0 : (blockIdx.z == 1) ? W1
                    : (blockIdx.z == 2) ? W2 : W3;
    bf16* out = Wt + (size_t)blockIdx.z * DD * DD;
    int tx = threadIdx.x, ty = threadIdx.y;
    int x0 = blockIdx.x * 32, y0 = blockIdx.y * 32;
#pragma unroll
    for (int i = 0; i < 32; i += 8)
        tile[ty + i][tx] = W[(size_t)(y0 + ty + i) * DD + x0 + tx];
    __syncthreads();
#pragma unroll
    for (int i = 0; i < 32; i += 8)
        out[(size_t)(x0 + ty + i) * DD + y0 + tx] = (bf16)tile[tx][ty + i];
}

// ---------------------------------------------------------------------------
// GEMM: C[M,N] = A[M,K] * W[K,N] + bias, via Wt[N,K] (B^T form), bf16 MFMA.
// 128x128 block tile, 4 waves in 2x2, each wave 64x64 (4x4 MFMA 16x16x32).
// BK=64 as two [128][32] K-panels; 16 K-iterations.
// MODE 0: QKV fused (z==0 Q: scaled by 0.125*log2e for exp2 softmax).
//         z==0/1 (Q,K): bf16 out [B*H, N, HD];
//         z==2 (V): bf16 out [B*H, HD, N] with per-32-tok kv permutation
//         (see flash PV): pos p <- orig o(p) = (p>>3)*4 + ((p>>2)&1)*16 + (p&3).
//         Epilogue staged through LDS in two 64-row passes (Cs aliased).
// MODE 1: out-projection, f32 output, plain [M, N].
// ---------------------------------------------------------------------------
template <int MODE>
__global__ __launch_bounds__(256) void gemm_bt(
    const bf16* __restrict__ A, const bf16* __restrict__ Wt,
    const float* __restrict__ b0, const float* __restrict__ b1,
    const float* __restrict__ b2, void* __restrict__ out0,
    void* __restrict__ out1, void* __restrict__ out2) {
    const int K = DD;
    // As = smem[0..8192), Bs = smem[8192..16384) (each 2 panels of [128][32]).
    // MODE0 epilogue: Cs (64x136 = 8704 elems) aliases smem (guarded).
    __shared__ __align__(16) bf16 smem[128 * 128];
    bf16* As = smem;
    bf16* Bs = smem + 128 * 64;
    bf16* Cs = smem; // MODE 0 epilogue alias (per-64-row pass)

    int m0 = blockIdx.x * 128;
    int n0 = blockIdx.y * 128;

    const bf16* Wz;
    const float* bias;
    void* out;
    float scale = 1.0f;
    int z = 0;
    if (MODE == 0) {
        z = blockIdx.z;
        Wz = Wt + (size_t)z * DD * DD;
        bias = (z == 0) ? b0 : ((z == 1) ? b1 : b2);
        out = (z == 0) ? out0 : ((z == 1) ? out1 : out2);
        if (z == 0) scale = 0.125f * 1.44269504f; // (1/sqrt(HD)) * log2(e)
    } else {
        Wz = Wt; bias = b0; out = out0;
    }

    int tid = threadIdx.x;
    int w = tid >> 6, lane = tid & 63;
    int wm = w >> 1, wn = w & 1;
    int quad = lane >> 4, l16 = lane & 15;

    f32x4 acc[4][4];
#pragma unroll
    for (int i = 0; i < 4; i++)
#pragma unroll
        for (int j = 0; j < 4; j++) acc[i][j] = (f32x4){0.f, 0.f, 0.f, 0.f};

    // Staging coords: chunk c in 0..1023 per operand; panel = c>>9,
    // row = (c&511)>>2, col = panel*32 + (c&3)*8. LDS dest = base + c*8
    // (linear, = wave-uniform base + lane*16 per j-group).
    for (int k0 = 0; k0 < K; k0 += 64) {
        __syncthreads(); // previous iteration's LDS reads complete
#pragma unroll
        for (int j = 0; j < 4; j++) {
            int c = j * 256 + w * 64 + lane;
            int row = (c & 511) >> 2;
            int col = (c >> 9) * 32 + (c & 3) * 8;
            async_copy16(&As[c * 8], &A[(size_t)(m0 + row) * K + k0 + col]);
            async_copy16(&Bs[c * 8], &Wz[(size_t)(n0 + row) * K + k0 + col]);
        }
        __syncthreads(); // drains vmcnt(0) before barrier

#pragma unroll
        for (int ks = 0; ks < 2; ks++) {
            bf16x8 af[4], bfm[4];
#pragma unroll
            for (int i = 0; i < 4; i++) {
                af[i] = *(const bf16x8*)&As[ks * 4096 + (wm * 64 + i * 16 + l16) * 32 + quad * 8];
                bfm[i] = *(const bf16x8*)&Bs[ks * 4096 + (wn * 64 + i * 16 + l16) * 32 + quad * 8];
            }
#pragma unroll
            for (int i = 0; i < 4; i++)
#pragma unroll
                for (int j = 0; j < 4; j++)
                    acc[i][j] = __builtin_amdgcn_mfma_f32_16x16x32_bf16(
                        af[i], bfm[j], acc[i][j], 0, 0, 0);
        }
    }

    // Epilogue. C/D layout: col = lane&15, row = quad*4 + reg.
    if (MODE == 0) {
        int bidx = m0 >> 11;          // batch (tile never crosses batch)
        int tok0 = m0 & (NN - 1);
        int hh0 = n0 >> 6;            // first of the 2 heads this tile covers
        __syncthreads(); // all waves' As/Bs reads done before Cs overwrites

#pragma unroll
        for (int hb = 0; hb < 2; hb++) {
            if (hb) __syncthreads(); // pass-0 write-out done before restage
            // Stage 64 rows of the bias-applied bf16 C-tile.
            // z<2: rows = m-local (waves wm==hb); Cs[(ml-64hb)*136 + nl].
            // z==2: rows = n-local (waves wn==hb); Cs[(nl-64hb)*136 + ml].
            if (z != 2) {
                if (wm == hb) {
#pragma unroll
                    for (int j = 0; j < 4; j++) {
                        int nl = wn * 64 + j * 16 + l16;
                        float bv = bias[n0 + nl];
#pragma unroll
                        for (int i = 0; i < 4; i++) {
#pragma unroll
                            for (int r = 0; r < 4; r++) {
                                int mlh = i * 16 + quad * 4 + r; // 0..63
                                Cs[mlh * 136 + nl] =
                                    (bf16)((acc[i][j][r] + bv) * scale);
                            }
                        }
                    }
                }
            } else {
                if (wn == hb) {
#pragma unroll
                    for (int j = 0; j < 4; j++) {
                        int nlh = j * 16 + l16; // 0..63 (= hd for head hb)
                        float bv = bias[n0 + hb * 64 + nlh];
#pragma unroll
                        for (int i = 0; i < 4; i++) {
#pragma unroll
                            for (int r = 0; r < 4; r++) {
                                int ml = wm * 64 + i * 16 + quad * 4 + r;
                                Cs[nlh * 136 + ml] = (bf16)(acc[i][j][r] + bv);
                            }
                        }
                    }
                }
            }
            __syncthreads();

            if (z != 2) {
                // out [bh][tok][hd]: tokens tok0+64hb..+64, both heads.
#pragma unroll
                for (int hf = 0; hf < 2; hf++) {
                    bf16* base = (bf16*)out +
                        ((size_t)(bidx * HH + hh0 + hf) * NN + tok0 + hb * 64) * HD;
#pragma unroll
                    for (int k = 0; k < 2; k++) {
                        int f = k * 2048 + tid * 8; // 0..4095; tok=f>>6, hd=f&63
                        *(bf16x8*)&base[f] =
                            *(const bf16x8*)&Cs[(f >> 6) * 136 + hf * 64 + (f & 63)];
                    }
                }
            } else {
                // V^T out [bh][hd][tok], head hb only, kv-permuted per 32-tok
                // block: dst pos p holds orig o(p)=(p>>3)*4+((p>>2)&1)*16+(p&3).
#pragma unroll
                for (int k = 0; k < 4; k++) {
                    int hd = k * 16 + (tid >> 4);     // 0..63
                    int p0 = (tid & 15) * 8;
                    int base32 = p0 & ~31;
                    int qq = (p0 & 31) >> 3;
                    const bf16* crow = &Cs[hd * 136];
                    bf16x4 lo = *(const bf16x4*)&crow[base32 + qq * 4];
                    bf16x4 hi = *(const bf16x4*)&crow[base32 + qq * 4 + 16];
                    bf16x8 v = __builtin_shufflevector(lo, hi, 0, 1, 2, 3, 4, 5, 6, 7);
                    bf16* dst = (bf16*)out +
                        ((size_t)(bidx * HH + hh0 + hb) * HD + hd) * NN + tok0 + p0;
                    *(bf16x8*)dst = v;
                }
            }
        }
    } else {
#pragma unroll
        for (int j = 0; j < 4; j++) {
            int n = n0 + wn * 64 + j * 16 + l16;
            float bv = bias[n];
#pragma unroll
            for (int i = 0; i < 4; i++) {
                int mrow = m0 + wm * 64 + i * 16 + quad * 4;
#pragma unroll
                for (int r = 0; r < 4; r++)
                    ((float*)out)[(size_t)(mrow + r) * DD + n] = acc[i][j][r] + bv;
            }
        }
    }
}

// ---------------------------------------------------------------------------
// Flash attention (causal, no-max softmax) — R17: R16 + setprio around MFMA.
// grid = (B*H, 8), block = 512 threads (8 waves x 16 q-rows = 128-row q-tile).
// bh on blockIdx.x -> linear id%8 == bh%8 -> XCD L2 affinity for K/V.
// Block does q-tiles qi=blockIdx.y and 15-blockIdx.y: every block exactly
// 17 tile-iters (balanced residency — occupancy is a time integral).
// Swapped QK^T: s = mfma(K,Q) -> lane holds P[q=l16][kv=band*16+quad*4+r].
// PV at K=32: pfrag = concat(band 2mi, band 2mi+1); V^T is kv-permuted in
// memory so the B-frag is ONE b128 whose element j matches pfrag's kv map.
// Per iter: [issue loads t+1 -> compute t from buf(t&1) -> ds_write t+1 into
// buf(t&1^1) -> barrier]: writes overlap compute, loads hide under compute.
// ---------------------------------------------------------------------------
__global__ __launch_bounds__(512, 4) void flash_attn(
    const bf16* __restrict__ Q, const bf16* __restrict__ Kg,
    const bf16* __restrict__ Vt_g, bf16* __restrict__ Oc) {
    __shared__ __align__(16) bf16 Ks[2][128 * 72];   // [kv][hd], stride 72
    __shared__ __align__(16) bf16 Vs[2][64 * 136];   // [d][kv-perm], stride 136

    int bh = blockIdx.x;              // linear id % 8 == bh % 8 -> XCD locality
    int b = bh >> 4, h = bh & 15;
    int tid = threadIdx.x;
    int w = tid >> 6, lane = tid & 63;
    int quad = lane >> 4, l16 = lane & 15;

    const bf16* Qb = Q + (size_t)bh * NN * HD;
    const bf16* Kb = Kg + (size_t)bh * NN * HD;
    const bf16* Vtb = Vt_g + (size_t)bh * HD * NN;

    bf16x8 ones8;
#pragma unroll
    for (int i = 0; i < 8; i++) ones8[i] = (bf16)1.0f;

    // Per-thread staging coordinates (fixed across tiles). 512 threads stage
    // a 128x64 K-tile and a 64x128 V^T-tile with 2 b128 chunks each.
    int kr[2], kc[2], vd[2], vk[2];
#pragma unroll
    for (int j = 0; j < 2; j++) {
        int c = j * 512 + tid;
        kr[j] = c >> 3; kc[j] = (c & 7) * 8;   // K: row, col-chunk
        vd[j] = c >> 4; vk[j] = (c & 15) * 8;  // V^T: d, kv-chunk
    }

    for (int phase = 0; phase < 2; phase++) {
        int qi = (phase == 0) ? blockIdx.y : (15 - blockIdx.y);
        int q0 = qi * 128;
        int qrow = q0 + w * 16 + l16;          // this lane's q (qf col & mask)

        // This wave's Q fragments (B-operand for swapped mfma: col=l16=q,
        // k = ks*32 + quad*8 + j over HD).
        bf16x8 qf[2];
#pragma unroll
        for (int ks = 0; ks < 2; ks++)
            qf[ks] = *(const bf16x8*)&Qb[(size_t)qrow * HD + ks * 32 + quad * 8];

        f32x4 l_sum = (f32x4){0.f, 0.f, 0.f, 0.f};
        f32x4 o_acc[4];
#pragma unroll
        for (int di = 0; di < 4; di++) o_acc[di] = (f32x4){0.f, 0.f, 0.f, 0.f};

        // Prologue: tile 0 -> regs -> buf 0 -> barrier.
        bf16x8 kreg[2], vreg[2];
#pragma unroll
        for (int j = 0; j < 2; j++) {
            kreg[j] = *(const bf16x8*)&Kb[(size_t)kr[j] * HD + kc[j]];
            vreg[j] = *(const bf16x8*)&Vtb[(size_t)vd[j] * NN + vk[j]];
        }
#pragma unroll
        for (int j = 0; j < 2; j++) {
            *(bf16x8*)&Ks[0][kr[j] * 72 + kc[j]] = kreg[j];
            *(bf16x8*)&Vs[0][vd[j] * 136 + vk[j]] = vreg[j];
        }
        __syncthreads();

        for (int t = 0; t <= qi; t++) {
            int cur = t & 1;
            // Issue loads for tile t+1 first (latency hides under compute).
            if (t < qi) {
                int kvn = (t + 1) * 128;
#pragma unroll
                for (int j = 0; j < 2; j++) {
                    kreg[j] = *(const bf16x8*)&Kb[(size_t)(kvn + kr[j]) * HD + kc[j]];
                    vreg[j] = *(const bf16x8*)&Vtb[(size_t)vd[j] * NN + kvn + vk[j]];
                }
            }

            const bf16* Kcur = Ks[cur];
            const bf16* Vcur = Vs[cur];
            int kv0 = t * 128;
            bool diag = (t == qi);
            // Per 32-kv band-pair mi: bands a=2mi, b=2mi+1.
#pragma unroll
            for (int mi = 0; mi < 4; mi++) {
                int ba = 2 * mi, bb = 2 * mi + 1;
                bf16x8 ka0 = *(const bf16x8*)&Kcur[(ba * 16 + l16) * 72 + quad * 8];
                bf16x8 ka1 = *(const bf16x8*)&Kcur[(ba * 16 + l16) * 72 + 32 + quad * 8];
                bf16x8 kb0 = *(const bf16x8*)&Kcur[(bb * 16 + l16) * 72 + quad * 8];
                bf16x8 kb1 = *(const bf16x8*)&Kcur[(bb * 16 + l16) * 72 + 32 + quad * 8];
                f32x4 sa = (f32x4){0.f, 0.f, 0.f, 0.f};
                f32x4 sb = (f32x4){0.f, 0.f, 0.f, 0.f};
                __builtin_amdgcn_s_setprio(1);
                sa = __builtin_amdgcn_mfma_f32_16x16x32_bf16(ka0, qf[0], sa, 0, 0, 0);
                sa = __builtin_amdgcn_mfma_f32_16x16x32_bf16(ka1, qf[1], sa, 0, 0, 0);
                sb = __builtin_amdgcn_mfma_f32_16x16x32_bf16(kb0, qf[0], sb, 0, 0, 0);
                sb = __builtin_amdgcn_mfma_f32_16x16x32_bf16(kb1, qf[1], sb, 0, 0, 0);
                __builtin_amdgcn_s_setprio(0);
                // lane holds S[qrow][kv0 + band*16 + quad*4 + r], r=0..3.
                bf16x4 pa4, pb4;
                if (diag) {
                    int kva = kv0 + ba * 16 + quad * 4;
                    int kvb = kv0 + bb * 16 + quad * 4;
#pragma unroll
                    for (int r = 0; r < 4; r++) {
                        pa4[r] = (bf16)((kva + r > qrow) ? 0.f : exp2f(sa[r]));
                        pb4[r] = (bf16)((kvb + r > qrow) ? 0.f : exp2f(sb[r]));
                    }
                } else {
#pragma unroll
                    for (int r = 0; r < 4; r++) {
                        pa4[r] = (bf16)exp2f(sa[r]);
                        pb4[r] = (bf16)exp2f(sb[r]);
                    }
                }
                // K=32 A-frag: j=0..3 -> band a (kv=32mi+quad*4+j),
                //              j=4..7 -> band b (kv=32mi+16+quad*4+(j-4)).
                bf16x8 pfrag = __builtin_shufflevector(pa4, pb4, 0, 1, 2, 3, 4, 5, 6, 7);
                __builtin_amdgcn_s_setprio(1);
                l_sum = __builtin_amdgcn_mfma_f32_16x16x32_bf16(pfrag, ones8, l_sum, 0, 0, 0);
                // B-frag: ONE b128 — V^T kv-permuted in memory so position
                // quad*8+j holds V[same kv as pfrag element j][d].
#pragma unroll
                for (int di = 0; di < 4; di++) {
                    bf16x8 vfrag = *(const bf16x8*)&Vcur[(di * 16 + l16) * 136 + mi * 32 + quad * 8];
                    o_acc[di] = __builtin_amdgcn_mfma_f32_16x16x32_bf16(pfrag, vfrag, o_acc[di], 0, 0, 0);
                }
                __builtin_amdgcn_s_setprio(0);
            }

            // Commit tile t+1 into the other buffer (overlaps nothing serial;
            // vmcnt wait for the loads lands here, hidden by compute above).
            if (t < qi) {
                bf16* Kn = Ks[cur ^ 1];
                bf16* Vn = Vs[cur ^ 1];
#pragma unroll
                for (int j = 0; j < 2; j++) {
                    *(bf16x8*)&Kn[kr[j] * 72 + kc[j]] = kreg[j];
                    *(bf16x8*)&Vn[vd[j] * 136 + vk[j]] = vreg[j];
                }
            }
            __syncthreads();
        }

        // Epilogue: O/l -> [B, N, H*HD] (concat-head layout for the O-proj GEMM)
        // C-layout: row = q = quad*4 + r (within wave's 16), col = d = l16.
#pragma unroll
        for (int r = 0; r < 4; r++) {
            float inv = 1.0f / l_sum[r];
            int tok = q0 + w * 16 + quad * 4 + r;
#pragma unroll
            for (int di = 0; di < 4; di++) {
                int d = h * 64 + di * 16 + l16;
                Oc[((size_t)(b * NN + tok)) * DD + d] = (bf16)(o_acc[di][r] * inv);
            }
        }
    }
}

// ---------------------------------------------------------------------------
extern "C" void kernel_launch(void* const* d_in, const int* in_sizes, int n_in,
                              void* d_out, int out_size, void* d_ws, size_t ws_size,
                              hipStream_t stream) {
    const float* x  = (const float*)d_in[0];
    const float* Wq = (const float*)d_in[1];
    const float* bq = (const float*)d_in[2];
    const float* Wk = (const float*)d_in[3];
    const float* bk = (const float*)d_in[4];
    const float* Wv = (const float*)d_in[5];
    const float* bv = (const float*)d_in[6];
    const float* Wo = (const float*)d_in[7];
    const float* bo = (const float*)d_in[8];

    const size_t need = (size_t)(8388608ull * 5 + 4194304ull) * sizeof(bf16);
    if (ws_size < need) return; // diagnostic: leaves d_out zeroed (absmax 3.8125)

    bf16* ws = (bf16*)d_ws;
    bf16* xb = ws;
    bf16* wt = xb + (size_t)MM * DD;
    bf16* Qw = wt + 4ull * DD * DD;       // [B*H, N, HD], pre-scaled 0.125*log2e
    bf16* Kw = Qw + (size_t)MM * DD;      // [B*H, N, HD]
    bf16* Vw = Kw + (size_t)MM * DD;      // V^T [B*H, HD, N], kv-permuted
    bf16* Aw = Vw + (size_t)MM * DD;      // attention out [B, N, D]

    convert_x<<<dim3(MM * DD / 2048), 256, 0, stream>>>(x, xb);

    transpose_w4<<<dim3(32, 32, 4), dim3(32, 8), 0, stream>>>(Wq, Wk, Wv, Wo, wt);

    gemm_bt<0><<<dim3(MM / 128, DD / 128, 3), 256, 0, stream>>>(
        xb, wt, bq, bk, bv, Qw, Kw, Vw);

    // grid (bh, 8): bh%8 -> XCD affinity; paired qi/15-qi -> every block
    // exactly 17 tile-iters (balanced residency).
    flash_attn<<<dim3(BB * HH, 8), 512, 0, stream>>>(Qw, Kw, Vw, Aw);

    gemm_bt<1><<<dim3(MM / 128, DD / 128, 1), 256, 0, stream>>>(
        Aw, wt + 3ull * DD * DD, bo, bo, bo, d_out, d_out, d_out);
}